// Round 1
// baseline (7320.457 us; speedup 1.0000x reference)
//
#include <hip/hip_runtime.h>

#define B_ROWS  2048
#define T_STEPS 112
#define N1 1300
#define N2 340
#define N3 1400
#define CH1 21   // ceil(1300/64)
#define CH2 6    // ceil(340/64)
#define CH3 22   // ceil(1400/64)

// d_ws float offsets
#define OFF_W2T 0          // [1300][340]
#define OFF_W3T 442000     // [340][1400]
#define OFF_W4T 918000     // [1400][4]
#define OFF_BS1 923600     // 1300
#define OFF_BS2 924900     // 340
#define OFF_BS3 925240     // 1400
#define OFF_BS4 926640     // 4
#define WS_FLOATS 926644

__global__ __launch_bounds__(256) void snn_prep(
    const float* __restrict__ W2, const float* __restrict__ W3, const float* __restrict__ W4,
    const float* __restrict__ b1, const float* __restrict__ bias1,
    const float* __restrict__ b2, const float* __restrict__ bias2,
    const float* __restrict__ b3, const float* __restrict__ bias3,
    const float* __restrict__ b4, const float* __restrict__ bias4,
    float* __restrict__ ws)
{
    for (int idx = blockIdx.x * blockDim.x + threadIdx.x; idx < WS_FLOATS;
         idx += gridDim.x * blockDim.x) {
        float v;
        if (idx < OFF_W3T) {                       // W2T[i][k] = W2[k][i]
            int j = idx; int i = j / N2, k = j % N2;
            v = W2[k * N1 + i];
        } else if (idx < OFF_W4T) {                // W3T[i][k] = W3[k][i]
            int j = idx - OFF_W3T; int i = j / N3, k = j % N3;
            v = W3[k * N2 + i];
        } else if (idx < OFF_BS1) {                // W4T[i][k] = W4[k][i]
            int j = idx - OFF_W4T; int i = j / 4, k = j % 4;
            v = W4[k * N3 + i];
        } else if (idx < OFF_BS2) { int j = idx - OFF_BS1; v = b1[j] + bias1[j]; }
        else if (idx < OFF_BS3)   { int j = idx - OFF_BS2; v = b2[j] + bias2[j]; }
        else if (idx < OFF_BS4)   { int j = idx - OFF_BS3; v = b3[j] + bias3[j]; }
        else                      { int j = idx - OFF_BS4; v = b4[j] + bias4[j]; }
        ws[idx] = v;
    }
}

// One block per batch row; 4 waves split each layer's neurons into 64-aligned
// chunk ranges. Spikes are exchanged as 64-bit ballot masks in LDS; consumers
// iterate set bits (wave-uniform) so inactive inputs cost nothing.
__global__ __launch_bounds__(256) void snn_main(
    const float* __restrict__ x,
    const float* __restrict__ W1,
    const float* __restrict__ ws,
    const float* __restrict__ thr4p,
    float* __restrict__ out)
{
    const int b    = blockIdx.x;
    const int wave = threadIdx.x >> 6;
    const int lane = threadIdx.x & 63;

    const float* __restrict__ W2T = ws + OFF_W2T;
    const float* __restrict__ W3T = ws + OFF_W3T;
    const float* __restrict__ W4T = ws + OFF_W4T;
    const float* __restrict__ bs1 = ws + OFF_BS1;
    const float* __restrict__ bs2 = ws + OFF_BS2;
    const float* __restrict__ bs3 = ws + OFF_BS3;
    const float* __restrict__ bs4 = ws + OFF_BS4;

    __shared__ unsigned long long sm1[CH1];
    __shared__ unsigned long long sm2[CH2];
    __shared__ unsigned long long sm3[CH3];

    // chunk ownership per wave: L1 21 = 6+5+5+5, L2 6 = 2+2+1+1, L3 22 = 6+6+5+5
    const int c1b = (wave == 0) ? 0 : (wave == 1) ? 6 : (wave == 2) ? 11 : 16;
    const int n1  = (wave == 0) ? 6 : 5;
    const int c2b = (wave == 0) ? 0 : (wave == 1) ? 2 : (wave == 2) ? 4 : 5;
    const int n2  = (wave < 2) ? 2 : 1;
    const int c3b = (wave == 0) ? 0 : (wave == 1) ? 6 : (wave == 2) ? 12 : 17;
    const int n3  = (wave < 2) ? 6 : 5;

    float mem1[6] = {0.f,0.f,0.f,0.f,0.f,0.f};
    float mem2[2] = {0.f,0.f};
    float mem3[6] = {0.f,0.f,0.f,0.f,0.f,0.f};
    float mem4 = 0.f;
    float cnt  = 0.f;
    const float thr4 = thr4p[0];

    const float4* __restrict__ xv4 = (const float4*)x;
    const float4* __restrict__ W1v = (const float4*)W1;

    for (int t = 0; t < T_STEPS; ++t) {
        float4 xv = xv4[b * T_STEPS + t];
        const float x0 = xv.x / 50.0f + 0.001f;
        const float x1 = xv.y / 50.0f + 0.001f;
        const float x2 = xv.z / 50.0f + 0.001f;
        const float x3 = xv.w / 50.0f + 0.001f;

        // ---------- layer 1 (dense 4-input) + LIF ----------
        #pragma unroll
        for (int u = 0; u < 6; ++u) {
            if (u < n1) {
                const int c = c1b + u;
                const int k = c * 64 + lane;
                const bool valid = (k < N1);
                float h = 0.f;
                if (valid) {
                    float4 w = W1v[k];
                    h = bs1[k] + w.x * x0 + w.y * x1 + w.z * x2 + w.w * x3;
                }
                float m = mem1[u];
                const float r = (m > 1.0f) ? 1.0f : 0.0f;  // reset from PREVIOUS mem
                m = 0.9f * m + h - r;
                mem1[u] = m;
                const bool s = valid && (m > 1.0f);
                const unsigned long long bal = __ballot(s);
                if (lane == 0) sm1[c] = bal;
            }
        }
        __syncthreads();

        // ---------- layer 2 (sparse gather over active s1) + LIF ----------
        float h2[2]; int k2[2]; bool v2[2];
        #pragma unroll
        for (int u = 0; u < 2; ++u) {
            k2[u] = (c2b + u) * 64 + lane;
            v2[u] = (u < n2) && (k2[u] < N2);
            h2[u] = v2[u] ? bs2[k2[u]] : 0.f;
        }
        for (int c = 0; c < CH1; ++c) {
            unsigned long long m = sm1[c];
            const int base = c * 64;
            while (m) {
                const int i = base + __builtin_ctzll(m);
                m &= (m - 1);
                const float* wr = W2T + i * N2;
                #pragma unroll
                for (int u = 0; u < 2; ++u)
                    if (v2[u]) h2[u] += wr[k2[u]];
            }
        }
        #pragma unroll
        for (int u = 0; u < 2; ++u) {
            if (u < n2) {
                const int c = c2b + u;
                const int k = c * 64 + lane;
                const bool valid = (k < N2);
                float m = mem2[u];
                const float r = (m > 1.0f) ? 1.0f : 0.0f;
                m = 0.9f * m + h2[u] - r;
                mem2[u] = m;
                const bool s = valid && (m > 1.0f);
                const unsigned long long bal = __ballot(s);
                if (lane == 0) sm2[c] = bal;
            }
        }
        __syncthreads();

        // ---------- layer 3 (sparse gather over active s2) + LIF ----------
        float h3[6]; int k3[6]; bool v3[6];
        #pragma unroll
        for (int u = 0; u < 6; ++u) {
            k3[u] = (c3b + u) * 64 + lane;
            v3[u] = (u < n3) && (k3[u] < N3);
            h3[u] = v3[u] ? bs3[k3[u]] : 0.f;
        }
        for (int c = 0; c < CH2; ++c) {
            unsigned long long m = sm2[c];
            const int base = c * 64;
            while (m) {
                const int i = base + __builtin_ctzll(m);
                m &= (m - 1);
                const float* wr = W3T + i * N3;
                #pragma unroll
                for (int u = 0; u < 6; ++u)
                    if (v3[u]) h3[u] += wr[k3[u]];
            }
        }
        #pragma unroll
        for (int u = 0; u < 6; ++u) {
            if (u < n3) {
                const int c = c3b + u;
                const int k = c * 64 + lane;
                const bool valid = (k < N3);
                float m = mem3[u];
                const float r = (m > 1.0f) ? 1.0f : 0.0f;
                m = 0.9f * m + h3[u] - r;
                mem3[u] = m;
                const bool s = valid && (m > 1.0f);
                const unsigned long long bal = __ballot(s);
                if (lane == 0) sm3[c] = bal;
            }
        }
        __syncthreads();

        // ---------- layer 4 (4 outputs, wave 0 only; lanes 0-3) ----------
        if (wave == 0) {
            float h4 = (lane < 4) ? bs4[lane] : 0.f;
            for (int c = 0; c < CH3; ++c) {
                unsigned long long m = sm3[c];
                const int base = c * 64;
                while (m) {
                    const int i = base + __builtin_ctzll(m);
                    m &= (m - 1);
                    if (lane < 4) h4 += W4T[i * 4 + lane];
                }
            }
            float m4 = mem4;
            const float r4 = (m4 > thr4) ? thr4 : 0.f;
            m4 = 0.9f * m4 + h4 - r4;
            mem4 = m4;
            const float s4 = (m4 > thr4) ? 1.f : 0.f;
            if (lane < 4) {
                out[8192 + (b * T_STEPS + t) * 4 + lane] = s4;
                cnt += s4;
            }
        }
        // no barrier needed here: sm1 rewrites (layer 1, t+1) are fenced from
        // this step's readers by the barriers above (see hazard analysis).
    }

    if (wave == 0 && lane < 4) out[b * 4 + lane] = cnt;
}

extern "C" void kernel_launch(void* const* d_in, const int* in_sizes, int n_in,
                              void* d_out, int out_size, void* d_ws, size_t ws_size,
                              hipStream_t stream)
{
    const float* x     = (const float*)d_in[0];
    const float* W1    = (const float*)d_in[1];
    const float* b1    = (const float*)d_in[2];
    const float* bias1 = (const float*)d_in[3];
    const float* W2    = (const float*)d_in[4];
    const float* b2    = (const float*)d_in[5];
    const float* bias2 = (const float*)d_in[6];
    const float* W3    = (const float*)d_in[7];
    const float* b3    = (const float*)d_in[8];
    const float* bias3 = (const float*)d_in[9];
    const float* W4    = (const float*)d_in[10];
    const float* b4    = (const float*)d_in[11];
    const float* bias4 = (const float*)d_in[12];
    const float* thr4  = (const float*)d_in[13];
    float* out = (float*)d_out;
    float* ws  = (float*)d_ws;

    hipLaunchKernelGGL(snn_prep, dim3(1024), dim3(256), 0, stream,
                       W2, W3, W4, b1, bias1, b2, bias2, b3, bias3, b4, bias4, ws);
    hipLaunchKernelGGL(snn_main, dim3(B_ROWS), dim3(256), 0, stream,
                       x, W1, ws, thr4, out);
}

// Round 2
// 3993.690 us; speedup vs baseline: 1.8330x; 1.8330x over previous
//
#include <hip/hip_runtime.h>

#define B_ROWS  2048
#define T_STEPS 112
#define N1 1300
#define N2 340
#define N3 1400
#define CH1 21   // ceil(1300/64)
#define CH2 6    // ceil(340/64)
#define CH3 22   // ceil(1400/64)

// d_ws float offsets
#define OFF_W2T 0          // [1300][340]
#define OFF_W3T 442000     // [340][1400]
#define OFF_W4T 918000     // [1400][4]
#define OFF_BS1 923600     // 1300
#define OFF_BS2 924900     // 340
#define OFF_BS3 925240     // 1400
#define OFF_BS4 926640     // 4
#define WS_FLOATS 926644

__global__ __launch_bounds__(256) void snn_prep(
    const float* __restrict__ W2, const float* __restrict__ W3, const float* __restrict__ W4,
    const float* __restrict__ b1, const float* __restrict__ bias1,
    const float* __restrict__ b2, const float* __restrict__ bias2,
    const float* __restrict__ b3, const float* __restrict__ bias3,
    const float* __restrict__ b4, const float* __restrict__ bias4,
    float* __restrict__ ws)
{
    for (int idx = blockIdx.x * blockDim.x + threadIdx.x; idx < WS_FLOATS;
         idx += gridDim.x * blockDim.x) {
        float v;
        if (idx < OFF_W3T) {                       // W2T[i][k] = W2[k][i]
            int j = idx; int i = j / N2, k = j % N2;
            v = W2[k * N1 + i];
        } else if (idx < OFF_W4T) {                // W3T[i][k] = W3[k][i]
            int j = idx - OFF_W3T; int i = j / N3, k = j % N3;
            v = W3[k * N2 + i];
        } else if (idx < OFF_BS1) {                // W4T[i][k] = W4[k][i]
            int j = idx - OFF_W4T; int i = j / 4, k = j % 4;
            v = W4[k * N3 + i];
        } else if (idx < OFF_BS2) { int j = idx - OFF_BS1; v = b1[j] + bias1[j]; }
        else if (idx < OFF_BS3)   { int j = idx - OFF_BS2; v = b2[j] + bias2[j]; }
        else if (idx < OFF_BS4)   { int j = idx - OFF_BS3; v = b3[j] + bias3[j]; }
        else                      { int j = idx - OFF_BS4; v = b4[j] + bias4[j]; }
        ws[idx] = v;
    }
}

// One block per batch row. Spike masks are expanded into LDS index lists
// (parallel expansion: lane position = popcount of lower mask bits; chunk
// offsets via wave shuffle-scan). Gathers iterate the list with fixed unroll
// so 8-24 independent loads are in flight; adds stay in ascending-index
// serial order (bit-identical accumulation vs the validated round-1 kernel).
__global__ __launch_bounds__(256) void snn_main(
    const float* __restrict__ x,
    const float* __restrict__ W1,
    const float* __restrict__ ws,
    const float* __restrict__ thr4p,
    float* __restrict__ out)
{
    const int b    = blockIdx.x;
    const int wave = threadIdx.x >> 6;
    const int lane = threadIdx.x & 63;

    const float* __restrict__ W2T = ws + OFF_W2T;
    const float* __restrict__ W3T = ws + OFF_W3T;
    const float* __restrict__ W4T = ws + OFF_W4T;
    const float* __restrict__ bs1 = ws + OFF_BS1;
    const float* __restrict__ bs2 = ws + OFF_BS2;
    const float* __restrict__ bs3 = ws + OFF_BS3;
    const float* __restrict__ bs4 = ws + OFF_BS4;

    __shared__ unsigned short lst1[CH1 * 64];
    __shared__ unsigned short lst2[CH2 * 64];
    __shared__ unsigned short lst3[CH3 * 64];
    __shared__ int pcnt1[CH1];
    __shared__ int pcnt2[CH2];
    __shared__ int pcnt3[CH3];

    // chunk ownership: L1 21 = 6+5+5+5, L2 6 = 2+2+1+1, L3 22 = 6+6+5+5
    const int c1b = (wave == 0) ? 0 : (wave == 1) ? 6 : (wave == 2) ? 11 : 16;
    const int n1  = (wave == 0) ? 6 : 5;
    const int c2b = (wave == 0) ? 0 : (wave == 1) ? 2 : (wave == 2) ? 4 : 5;
    const int n2  = (wave < 2) ? 2 : 1;
    const int c3b = (wave == 0) ? 0 : (wave == 1) ? 6 : (wave == 2) ? 12 : 17;
    const int n3  = (wave < 2) ? 6 : 5;

    float mem1[6] = {0.f,0.f,0.f,0.f,0.f,0.f};
    float mem2[2] = {0.f,0.f};
    float mem3[6] = {0.f,0.f,0.f,0.f,0.f,0.f};
    float mem4 = 0.f;
    float cnt  = 0.f;
    const float thr4 = thr4p[0];

    const float4* __restrict__ xv4 = (const float4*)x;
    const float4* __restrict__ W1v = (const float4*)W1;

    // ---- hoist t-invariant per-lane setup ----
    int  k1v[6]; bool val1[6]; float bsv1[6];
    #pragma unroll
    for (int u = 0; u < 6; ++u) {
        k1v[u] = (c1b + u) * 64 + lane;
        val1[u] = (u < n1) && (k1v[u] < N1);
        bsv1[u] = val1[u] ? bs1[k1v[u]] : 0.f;
    }
    int k2v[2]; bool v2[2]; float h2i[2];
    #pragma unroll
    for (int u = 0; u < 2; ++u) {
        k2v[u] = (c2b + u) * 64 + lane;
        v2[u] = (u < n2) && (k2v[u] < N2);
        h2i[u] = v2[u] ? bs2[k2v[u]] : 0.f;
    }
    int k3v[6]; bool v3[6]; float h3i[6];
    #pragma unroll
    for (int u = 0; u < 6; ++u) {
        k3v[u] = (c3b + u) * 64 + lane;
        v3[u] = (u < n3) && (k3v[u] < N3);
        h3i[u] = v3[u] ? bs3[k3v[u]] : 0.f;
    }
    const float bs4v = (lane < 4) ? bs4[lane] : 0.f;

    for (int t = 0; t < T_STEPS; ++t) {
        float4 xv = xv4[b * T_STEPS + t];
        const float x0 = xv.x / 50.0f + 0.001f;
        const float x1 = xv.y / 50.0f + 0.001f;
        const float x2 = xv.z / 50.0f + 0.001f;
        const float x3 = xv.w / 50.0f + 0.001f;

        // ---------- layer 1 (dense 4-input) + LIF + ballot ----------
        unsigned long long bal1[6];
        #pragma unroll
        for (int u = 0; u < 6; ++u) {
            if (u < n1) {
                float h = 0.f;
                if (val1[u]) {
                    float4 w = W1v[k1v[u]];
                    h = bsv1[u] + w.x * x0 + w.y * x1 + w.z * x2 + w.w * x3;
                }
                float m = mem1[u];
                const float r = (m > 1.0f) ? 1.0f : 0.0f;
                m = 0.9f * m + h - r;
                mem1[u] = m;
                const bool sp = val1[u] && (m > 1.0f);
                bal1[u] = __ballot(sp);
                if (lane == 0) pcnt1[c1b + u] = __popcll(bal1[u]);
            }
        }
        __syncthreads();  // B1: pcnt1 complete

        // scan chunk counts -> offsets; expand masks -> index list
        int cnt1;
        {
            int p = (lane < CH1) ? pcnt1[lane] : 0;
            int sc = p;
            #pragma unroll
            for (int d = 1; d < 64; d <<= 1) { int v = __shfl_up(sc, d); if (lane >= d) sc += v; }
            cnt1 = __shfl(sc, CH1 - 1);
            const int excl = sc - p;
            #pragma unroll
            for (int u = 0; u < 6; ++u) {
                if (u < n1) {
                    const int c = c1b + u;
                    const int offc = __shfl(excl, c);
                    const unsigned long long m = bal1[u];
                    if ((m >> lane) & 1ull) {
                        const int pos = offc + __popcll(m & ((1ull << lane) - 1ull));
                        lst1[pos] = (unsigned short)(c * 64 + lane);
                    }
                }
            }
        }
        __syncthreads();  // B2: lst1 complete

        // ---------- layer 2: sparse gather, unroll 8 (16 loads in flight) ----------
        float h2[2] = { h2i[0], h2i[1] };
        {
            int j = 0;
            for (; j + 8 <= cnt1; j += 8) {
                int idx[8];
                #pragma unroll
                for (int g = 0; g < 8; ++g) idx[g] = lst1[j + g];
                float t0[8], t1[8];
                #pragma unroll
                for (int g = 0; g < 8; ++g) {
                    const float* wr = W2T + idx[g] * N2;
                    t0[g] = v2[0] ? wr[k2v[0]] : 0.f;
                    t1[g] = v2[1] ? wr[k2v[1]] : 0.f;
                }
                #pragma unroll
                for (int g = 0; g < 8; ++g) h2[0] += t0[g];
                #pragma unroll
                for (int g = 0; g < 8; ++g) h2[1] += t1[g];
            }
            for (; j < cnt1; ++j) {
                const float* wr = W2T + (int)lst1[j] * N2;
                if (v2[0]) h2[0] += wr[k2v[0]];
                if (v2[1]) h2[1] += wr[k2v[1]];
            }
        }
        unsigned long long bal2[2];
        #pragma unroll
        for (int u = 0; u < 2; ++u) {
            if (u < n2) {
                float m = mem2[u];
                const float r = (m > 1.0f) ? 1.0f : 0.0f;
                m = 0.9f * m + h2[u] - r;
                mem2[u] = m;
                const bool sp = v2[u] && (m > 1.0f);
                bal2[u] = __ballot(sp);
                if (lane == 0) pcnt2[c2b + u] = __popcll(bal2[u]);
            }
        }
        __syncthreads();  // B3: pcnt2 complete

        int cnt2;
        {
            int p = (lane < CH2) ? pcnt2[lane] : 0;
            int sc = p;
            #pragma unroll
            for (int d = 1; d < 64; d <<= 1) { int v = __shfl_up(sc, d); if (lane >= d) sc += v; }
            cnt2 = __shfl(sc, CH2 - 1);
            const int excl = sc - p;
            #pragma unroll
            for (int u = 0; u < 2; ++u) {
                if (u < n2) {
                    const int c = c2b + u;
                    const int offc = __shfl(excl, c);
                    const unsigned long long m = bal2[u];
                    if ((m >> lane) & 1ull) {
                        const int pos = offc + __popcll(m & ((1ull << lane) - 1ull));
                        lst2[pos] = (unsigned short)(c * 64 + lane);
                    }
                }
            }
        }
        __syncthreads();  // B4: lst2 complete

        // ---------- layer 3: sparse gather, unroll 4 (24 loads in flight) ----------
        float h3[6] = { h3i[0], h3i[1], h3i[2], h3i[3], h3i[4], h3i[5] };
        {
            int j = 0;
            for (; j + 4 <= cnt2; j += 4) {
                int idx[4];
                #pragma unroll
                for (int g = 0; g < 4; ++g) idx[g] = lst2[j + g];
                float tv[4][6];
                #pragma unroll
                for (int g = 0; g < 4; ++g) {
                    const float* wr = W3T + idx[g] * N3;
                    #pragma unroll
                    for (int u = 0; u < 6; ++u)
                        tv[g][u] = v3[u] ? wr[k3v[u]] : 0.f;
                }
                #pragma unroll
                for (int u = 0; u < 6; ++u) {
                    #pragma unroll
                    for (int g = 0; g < 4; ++g) h3[u] += tv[g][u];
                }
            }
            for (; j < cnt2; ++j) {
                const float* wr = W3T + (int)lst2[j] * N3;
                #pragma unroll
                for (int u = 0; u < 6; ++u)
                    if (v3[u]) h3[u] += wr[k3v[u]];
            }
        }
        unsigned long long bal3[6];
        #pragma unroll
        for (int u = 0; u < 6; ++u) {
            if (u < n3) {
                float m = mem3[u];
                const float r = (m > 1.0f) ? 1.0f : 0.0f;
                m = 0.9f * m + h3[u] - r;
                mem3[u] = m;
                const bool sp = v3[u] && (m > 1.0f);
                bal3[u] = __ballot(sp);
                if (lane == 0) pcnt3[c3b + u] = __popcll(bal3[u]);
            }
        }
        __syncthreads();  // B5: pcnt3 complete

        int cnt3;
        {
            int p = (lane < CH3) ? pcnt3[lane] : 0;
            int sc = p;
            #pragma unroll
            for (int d = 1; d < 64; d <<= 1) { int v = __shfl_up(sc, d); if (lane >= d) sc += v; }
            cnt3 = __shfl(sc, CH3 - 1);
            const int excl = sc - p;
            #pragma unroll
            for (int u = 0; u < 6; ++u) {
                if (u < n3) {
                    const int c = c3b + u;
                    const int offc = __shfl(excl, c);
                    const unsigned long long m = bal3[u];
                    if ((m >> lane) & 1ull) {
                        const int pos = offc + __popcll(m & ((1ull << lane) - 1ull));
                        lst3[pos] = (unsigned short)(c * 64 + lane);
                    }
                }
            }
        }
        __syncthreads();  // B6: lst3 complete

        // ---------- layer 4 (wave 3; lanes 0-3), unroll 4 ----------
        if (wave == 3) {
            float h4 = bs4v;
            int j = 0;
            for (; j + 4 <= cnt3; j += 4) {
                int idx[4];
                #pragma unroll
                for (int g = 0; g < 4; ++g) idx[g] = lst3[j + g];
                float tw[4];
                #pragma unroll
                for (int g = 0; g < 4; ++g)
                    tw[g] = (lane < 4) ? W4T[idx[g] * 4 + lane] : 0.f;
                #pragma unroll
                for (int g = 0; g < 4; ++g) h4 += tw[g];
            }
            for (; j < cnt3; ++j)
                if (lane < 4) h4 += W4T[(int)lst3[j] * 4 + lane];

            float m4 = mem4;
            const float r4 = (m4 > thr4) ? thr4 : 0.f;
            m4 = 0.9f * m4 + h4 - r4;
            mem4 = m4;
            const float s4 = (m4 > thr4) ? 1.f : 0.f;
            if (lane < 4) {
                out[8192 + (b * T_STEPS + t) * 4 + lane] = s4;
                cnt += s4;
            }
        }
        // wave 3 lags into step t+1; all shared buffers it still reads (lst3)
        // are not rewritten until after B5 of t+1 -- safe.
    }

    if (wave == 3 && lane < 4) out[b * 4 + lane] = cnt;
}

extern "C" void kernel_launch(void* const* d_in, const int* in_sizes, int n_in,
                              void* d_out, int out_size, void* d_ws, size_t ws_size,
                              hipStream_t stream)
{
    const float* x     = (const float*)d_in[0];
    const float* W1    = (const float*)d_in[1];
    const float* b1    = (const float*)d_in[2];
    const float* bias1 = (const float*)d_in[3];
    const float* W2    = (const float*)d_in[4];
    const float* b2    = (const float*)d_in[5];
    const float* bias2 = (const float*)d_in[6];
    const float* W3    = (const float*)d_in[7];
    const float* b3    = (const float*)d_in[8];
    const float* bias3 = (const float*)d_in[9];
    const float* W4    = (const float*)d_in[10];
    const float* b4    = (const float*)d_in[11];
    const float* bias4 = (const float*)d_in[12];
    const float* thr4  = (const float*)d_in[13];
    float* out = (float*)d_out;
    float* ws  = (float*)d_ws;

    hipLaunchKernelGGL(snn_prep, dim3(1024), dim3(256), 0, stream,
                       W2, W3, W4, b1, bias1, b2, bias2, b3, bias3, b4, bias4, ws);
    hipLaunchKernelGGL(snn_main, dim3(B_ROWS), dim3(256), 0, stream,
                       x, W1, ws, thr4, out);
}

// Round 3
// 2591.468 us; speedup vs baseline: 2.8248x; 1.5411x over previous
//
#include <hip/hip_runtime.h>

#define B_ROWS  2048
#define T_STEPS 112
#define N1 1300
#define N2 340
#define N3 1400

// per-wave index-list region sizes (entries)
#define R1 384
#define R2 128
#define R3 384

// d_ws float offsets
#define OFF_W2T 0          // [1300][340]
#define OFF_W3T 442000     // [340][1400]
#define OFF_W4T 918000     // [1400][4]
#define OFF_BS1 923600     // 1300
#define OFF_BS2 924900     // 340
#define OFF_BS3 925240     // 1400
#define OFF_BS4 926640     // 4
#define WS_FLOATS 926644

__global__ __launch_bounds__(256) void snn_prep(
    const float* __restrict__ W2, const float* __restrict__ W3, const float* __restrict__ W4,
    const float* __restrict__ b1, const float* __restrict__ bias1,
    const float* __restrict__ b2, const float* __restrict__ bias2,
    const float* __restrict__ b3, const float* __restrict__ bias3,
    const float* __restrict__ b4, const float* __restrict__ bias4,
    float* __restrict__ ws)
{
    for (int idx = blockIdx.x * blockDim.x + threadIdx.x; idx < WS_FLOATS;
         idx += gridDim.x * blockDim.x) {
        float v;
        if (idx < OFF_W3T) {                       // W2T[i][k] = W2[k][i]
            int j = idx; int i = j / N2, k = j % N2;
            v = W2[k * N1 + i];
        } else if (idx < OFF_W4T) {                // W3T[i][k] = W3[k][i]
            int j = idx - OFF_W3T; int i = j / N3, k = j % N3;
            v = W3[k * N2 + i];
        } else if (idx < OFF_BS1) {                // W4T[i][k] = W4[k][i]
            int j = idx - OFF_W4T; int i = j / 4, k = j % 4;
            v = W4[k * N3 + i];
        } else if (idx < OFF_BS2) { int j = idx - OFF_BS1; v = b1[j] + bias1[j]; }
        else if (idx < OFF_BS3)   { int j = idx - OFF_BS2; v = b2[j] + bias2[j]; }
        else if (idx < OFF_BS4)   { int j = idx - OFF_BS3; v = b3[j] + bias3[j]; }
        else                      { int j = idx - OFF_BS4; v = b4[j] + bias4[j]; }
        ws[idx] = v;
    }
}

// Gather weight rows listed in per-wave compact regions of `lst` (entries are
// premultiplied row offsets). Per-output accumulation order is strictly
// ascending spike index (regions are ascending chunk ranges) — identical fp32
// rounding to the validated round-2 kernel.
template<int NOUT, int U>
__device__ __forceinline__ void gather_rows(
    const float* __restrict__ Wbase,
    const unsigned* lst, const int* wcnt, int region,
    const int* kk, float* h)
{
    for (int w = 0; w < 4; ++w) {
        const int n = wcnt[w];
        const unsigned* Lw = lst + w * region;
        int j = 0;
        for (; j + U <= n; j += U) {
            unsigned o[U];
            #pragma unroll
            for (int q = 0; q < U / 4; ++q) {
                uint4 ov = *(const uint4*)(Lw + j + 4 * q);
                o[4*q+0] = ov.x; o[4*q+1] = ov.y; o[4*q+2] = ov.z; o[4*q+3] = ov.w;
            }
            float tv[NOUT][U];
            #pragma unroll
            for (int g = 0; g < U; ++g) {
                const float* wr = Wbase + o[g];
                #pragma unroll
                for (int u = 0; u < NOUT; ++u) tv[u][g] = wr[kk[u]];
            }
            #pragma unroll
            for (int u = 0; u < NOUT; ++u) {
                #pragma unroll
                for (int g = 0; g < U; ++g) h[u] += tv[u][g];
            }
        }
        for (; j + 4 <= n; j += 4) {
            uint4 ov = *(const uint4*)(Lw + j);
            unsigned o[4] = { ov.x, ov.y, ov.z, ov.w };
            float tv[NOUT][4];
            #pragma unroll
            for (int g = 0; g < 4; ++g) {
                const float* wr = Wbase + o[g];
                #pragma unroll
                for (int u = 0; u < NOUT; ++u) tv[u][g] = wr[kk[u]];
            }
            #pragma unroll
            for (int u = 0; u < NOUT; ++u) {
                #pragma unroll
                for (int g = 0; g < 4; ++g) h[u] += tv[u][g];
            }
        }
        for (; j < n; ++j) {
            const float* wr = Wbase + Lw[j];
            #pragma unroll
            for (int u = 0; u < NOUT; ++u) h[u] += wr[kk[u]];
        }
    }
}

__global__ __launch_bounds__(256, 3) void snn_main(
    const float* __restrict__ x,
    const float* __restrict__ W1,
    const float* __restrict__ ws,
    const float* __restrict__ thr4p,
    float* __restrict__ out)
{
    const int b    = blockIdx.x;
    const int wave = threadIdx.x >> 6;
    const int lane = threadIdx.x & 63;

    const float* __restrict__ W2T = ws + OFF_W2T;
    const float* __restrict__ W3T = ws + OFF_W3T;
    const float* __restrict__ W4T = ws + OFF_W4T;
    const float* __restrict__ bs1 = ws + OFF_BS1;
    const float* __restrict__ bs2 = ws + OFF_BS2;
    const float* __restrict__ bs3 = ws + OFF_BS3;
    const float* __restrict__ bs4 = ws + OFF_BS4;

    __shared__ __align__(16) unsigned lst1[4 * R1];
    __shared__ __align__(16) unsigned lst2[4 * R2];
    __shared__ __align__(16) unsigned lst3[4 * R3];
    __shared__ int wcnt1[4], wcnt2[4], wcnt3[4];
    __shared__ float sbuf[T_STEPS * 4];

    // chunk ownership: L1 21 = 6+5+5+5, L2 6 = 2+2+1+1, L3 22 = 6+6+5+5
    const int c1b = (wave == 0) ? 0 : (wave == 1) ? 6 : (wave == 2) ? 11 : 16;
    const int n1  = (wave == 0) ? 6 : 5;
    const int c2b = (wave == 0) ? 0 : (wave == 1) ? 2 : (wave == 2) ? 4 : 5;
    const int n2  = (wave < 2) ? 2 : 1;
    const int c3b = (wave == 0) ? 0 : (wave == 1) ? 6 : (wave == 2) ? 12 : 17;
    const int n3  = (wave < 2) ? 6 : 5;

    float mem1[6] = {0.f,0.f,0.f,0.f,0.f,0.f};
    float mem2[2] = {0.f,0.f};
    float mem3[6] = {0.f,0.f,0.f,0.f,0.f,0.f};
    float mem4 = 0.f;
    float cnt  = 0.f;
    const float thr4 = thr4p[0];

    const float4* __restrict__ xv4 = (const float4*)x;
    const float4* __restrict__ W1v = (const float4*)W1;

    // ---- t-invariant per-lane setup ----
    int  k1v[6]; bool val1[6]; float bsv1[6];
    #pragma unroll
    for (int u = 0; u < 6; ++u) {
        k1v[u] = (c1b + u) * 64 + lane;
        val1[u] = (u < n1) && (k1v[u] < N1);
        bsv1[u] = val1[u] ? bs1[k1v[u]] : 0.f;
    }
    int kk2[2]; bool v2[2]; float h2i[2];
    #pragma unroll
    for (int u = 0; u < 2; ++u) {
        kk2[u] = (c2b + u) * 64 + lane;
        v2[u] = (u < n2) && (kk2[u] < N2);
        h2i[u] = v2[u] ? bs2[kk2[u]] : 0.f;
    }
    int kk3[6]; bool v3[6]; float h3i[6];
    #pragma unroll
    for (int u = 0; u < 6; ++u) {
        kk3[u] = (c3b + u) * 64 + lane;
        v3[u] = (u < n3) && (kk3[u] < N3);
        h3i[u] = v3[u] ? bs3[kk3[u]] : 0.f;
    }
    const float bs4v = bs4[lane & 3];
    const bool two2 = (wave < 2);
    const bool six3 = (wave < 2);

    for (int t = 0; t < T_STEPS; ++t) {
        float4 xv = xv4[b * T_STEPS + t];
        const float x0 = xv.x / 50.0f + 0.001f;
        const float x1 = xv.y / 50.0f + 0.001f;
        const float x2 = xv.z / 50.0f + 0.001f;
        const float x3 = xv.w / 50.0f + 0.001f;

        // ---------- phase 1: layer 1 + LIF + compact list ----------
        {
            unsigned woff = 0;
            #pragma unroll
            for (int u = 0; u < 6; ++u) {
                if (u < n1) {
                    float h = 0.f;
                    if (val1[u]) {
                        float4 wv = W1v[k1v[u]];
                        h = bsv1[u] + wv.x * x0 + wv.y * x1 + wv.z * x2 + wv.w * x3;
                    }
                    float m = mem1[u];
                    const float r = (m > 1.0f) ? 1.0f : 0.0f;
                    m = 0.9f * m + h - r;
                    mem1[u] = m;
                    const bool sp = val1[u] && (m > 1.0f);
                    const unsigned long long bal = __ballot(sp);
                    if (sp) {
                        const int pos = (int)woff + (int)__popcll(bal & ((1ull << lane) - 1ull));
                        lst1[wave * R1 + pos] = (unsigned)(k1v[u] * N2);  // premult row offset
                    }
                    woff += (unsigned)__popcll(bal);
                }
            }
            if (lane == 0) wcnt1[wave] = (int)woff;
        }
        __syncthreads();  // B1: lst1/wcnt1 ready

        // ---------- phase 2: layer-2 gather + LIF + compact list ----------
        {
            float h2[2] = { h2i[0], h2i[1] };
            if (two2) gather_rows<2, 16>(W2T, lst1, wcnt1, R1, kk2, h2);
            else      gather_rows<1, 16>(W2T, lst1, wcnt1, R1, kk2, h2);

            unsigned woff = 0;
            #pragma unroll
            for (int u = 0; u < 2; ++u) {
                if (u < n2) {
                    float m = mem2[u];
                    const float r = (m > 1.0f) ? 1.0f : 0.0f;
                    m = 0.9f * m + h2[u] - r;
                    mem2[u] = m;
                    const bool sp = v2[u] && (m > 1.0f);
                    const unsigned long long bal = __ballot(sp);
                    if (sp) {
                        const int pos = (int)woff + (int)__popcll(bal & ((1ull << lane) - 1ull));
                        lst2[wave * R2 + pos] = (unsigned)(kk2[u] * N3);
                    }
                    woff += (unsigned)__popcll(bal);
                }
            }
            if (lane == 0) wcnt2[wave] = (int)woff;
        }
        __syncthreads();  // B2: lst2/wcnt2 ready

        // ---------- phase 3: layer-3 gather + LIF + compact list ----------
        {
            float h3[6] = { h3i[0], h3i[1], h3i[2], h3i[3], h3i[4], h3i[5] };
            if (six3) gather_rows<6, 8>(W3T, lst2, wcnt2, R2, kk3, h3);
            else      gather_rows<5, 8>(W3T, lst2, wcnt2, R2, kk3, h3);

            unsigned woff = 0;
            #pragma unroll
            for (int u = 0; u < 6; ++u) {
                if (u < n3) {
                    float m = mem3[u];
                    const float r = (m > 1.0f) ? 1.0f : 0.0f;
                    m = 0.9f * m + h3[u] - r;
                    mem3[u] = m;
                    const bool sp = v3[u] && (m > 1.0f);
                    const unsigned long long bal = __ballot(sp);
                    if (sp) {
                        const int pos = (int)woff + (int)__popcll(bal & ((1ull << lane) - 1ull));
                        lst3[wave * R3 + pos] = (unsigned)(kk3[u] * 4);
                    }
                    woff += (unsigned)__popcll(bal);
                }
            }
            if (lane == 0) wcnt3[wave] = (int)woff;
        }
        __syncthreads();  // B3: lst3/wcnt3 ready

        // ---------- phase 4: layer 4 on wave 3, 64-lane parallel ----------
        // (other waves proceed to phase 1 of t+1; lst3 is not rewritten until
        //  after B2(t+1), which wave 3 reaches only after finishing here)
        if (wave == 3) {
            const int g16 = lane >> 2;
            const int o4  = lane & 3;
            float h4p = 0.f;
            for (int w = 0; w < 4; ++w) {
                const int n = wcnt3[w];
                const unsigned* Lw = lst3 + w * R3;
                int j = g16;
                for (; j + 48 < n; j += 64) {
                    float t0 = W4T[Lw[j]      + o4];
                    float t1 = W4T[Lw[j + 16] + o4];
                    float t2 = W4T[Lw[j + 32] + o4];
                    float t3 = W4T[Lw[j + 48] + o4];
                    h4p += t0; h4p += t1; h4p += t2; h4p += t3;
                }
                for (; j < n; j += 16) h4p += W4T[Lw[j] + o4];
            }
            #pragma unroll
            for (int d = 4; d < 64; d <<= 1) h4p += __shfl_xor(h4p, d);
            float h4 = bs4v + h4p;
            float m4 = mem4;
            const float r4 = (m4 > thr4) ? thr4 : 0.f;
            m4 = 0.9f * m4 + h4 - r4;
            mem4 = m4;
            const float s4 = (m4 > thr4) ? 1.f : 0.f;
            if (lane < 4) {
                sbuf[t * 4 + lane] = s4;
                cnt += s4;
            }
        }
    }

    __syncthreads();  // sbuf complete
    for (int i = threadIdx.x; i < T_STEPS * 4; i += 256)
        out[8192 + b * T_STEPS * 4 + i] = sbuf[i];
    if (wave == 3 && lane < 4) out[b * 4 + lane] = cnt;
}

extern "C" void kernel_launch(void* const* d_in, const int* in_sizes, int n_in,
                              void* d_out, int out_size, void* d_ws, size_t ws_size,
                              hipStream_t stream)
{
    const float* x     = (const float*)d_in[0];
    const float* W1    = (const float*)d_in[1];
    const float* b1    = (const float*)d_in[2];
    const float* bias1 = (const float*)d_in[3];
    const float* W2    = (const float*)d_in[4];
    const float* b2    = (const float*)d_in[5];
    const float* bias2 = (const float*)d_in[6];
    const float* W3    = (const float*)d_in[7];
    const float* b3    = (const float*)d_in[8];
    const float* bias3 = (const float*)d_in[9];
    const float* W4    = (const float*)d_in[10];
    const float* b4    = (const float*)d_in[11];
    const float* bias4 = (const float*)d_in[12];
    const float* thr4  = (const float*)d_in[13];
    float* out = (float*)d_out;
    float* ws  = (float*)d_ws;

    hipLaunchKernelGGL(snn_prep, dim3(1024), dim3(256), 0, stream,
                       W2, W3, W4, b1, bias1, b2, bias2, b3, bias3, b4, bias4, ws);
    hipLaunchKernelGGL(snn_main, dim3(B_ROWS), dim3(256), 0, stream,
                       x, W1, ws, thr4, out);
}

// Round 4
// 2199.057 us; speedup vs baseline: 3.3289x; 1.1784x over previous
//
#include <hip/hip_runtime.h>

#define B_ROWS  2048
#define T_STEPS 112
#define N1 1300
#define N2 340
#define N3 1400

// per-wave index-list region sizes (entries)
#define R1 384
#define R2 128
#define R3 384

// d_ws float offsets
#define OFF_W2T 0          // [1300][340]
#define OFF_W3T 442000     // [340][1400]
#define OFF_W4T 918000     // [1400][4]
#define OFF_BS1 923600     // 1300
#define OFF_BS2 924900     // 340
#define OFF_BS3 925240     // 1400
#define OFF_BS4 926640     // 4
#define WS_FLOATS 926644

__global__ __launch_bounds__(256) void snn_prep(
    const float* __restrict__ W2, const float* __restrict__ W3, const float* __restrict__ W4,
    const float* __restrict__ b1, const float* __restrict__ bias1,
    const float* __restrict__ b2, const float* __restrict__ bias2,
    const float* __restrict__ b3, const float* __restrict__ bias3,
    const float* __restrict__ b4, const float* __restrict__ bias4,
    float* __restrict__ ws)
{
    for (int idx = blockIdx.x * blockDim.x + threadIdx.x; idx < WS_FLOATS;
         idx += gridDim.x * blockDim.x) {
        float v;
        if (idx < OFF_W3T) {                       // W2T[i][k] = W2[k][i]
            int j = idx; int i = j / N2, k = j % N2;
            v = W2[k * N1 + i];
        } else if (idx < OFF_W4T) {                // W3T[i][k] = W3[k][i]
            int j = idx - OFF_W3T; int i = j / N3, k = j % N3;
            v = W3[k * N2 + i];
        } else if (idx < OFF_BS1) {                // W4T[i][k] = W4[k][i]
            int j = idx - OFF_W4T; int i = j / 4, k = j % 4;
            v = W4[k * N3 + i];
        } else if (idx < OFF_BS2) { int j = idx - OFF_BS1; v = b1[j] + bias1[j]; }
        else if (idx < OFF_BS3)   { int j = idx - OFF_BS2; v = b2[j] + bias2[j]; }
        else if (idx < OFF_BS4)   { int j = idx - OFF_BS3; v = b3[j] + bias3[j]; }
        else                      { int j = idx - OFF_BS4; v = b4[j] + bias4[j]; }
        ws[idx] = v;
    }
}

// Structure: each wave detects its own spikes and gathers the FULL weight row
// per spike with dwordx4 loads into per-wave partial accumulators; partials
// are reduced across waves in LDS at the LIF stage (thread-linear neuron
// ownership). 3 barriers per step; no cross-wave list traffic.
__global__ __launch_bounds__(256, 3) void snn_main(
    const float* __restrict__ x,
    const float* __restrict__ W1,
    const float* __restrict__ ws,
    const float* __restrict__ thr4p,
    float* __restrict__ out)
{
    const int b    = blockIdx.x;
    const int tid  = threadIdx.x;
    const int wave = tid >> 6;
    const int lane = tid & 63;

    const float* __restrict__ W2T = ws + OFF_W2T;
    const float* __restrict__ W3T = ws + OFF_W3T;
    const float* __restrict__ W4T = ws + OFF_W4T;
    const float* __restrict__ bs1 = ws + OFF_BS1;
    const float* __restrict__ bs2 = ws + OFF_BS2;
    const float* __restrict__ bs3 = ws + OFF_BS3;
    const float* __restrict__ bs4 = ws + OFF_BS4;

    __shared__ __align__(16) float pw2[4][340];
    __shared__ __align__(16) float pw3[4][1400];
    __shared__ __align__(16) unsigned lst1[4 * R1];
    __shared__ __align__(16) unsigned lst2[4 * R2];
    __shared__ __align__(16) unsigned lst3[4 * R3];
    __shared__ int wcnt3[4];
    __shared__ float sbuf[T_STEPS * 4];

    // layer-1 chunk ownership: 21 chunks = 6+5+5+5
    const int c1b = (wave == 0) ? 0 : (wave == 1) ? 6 : (wave == 2) ? 11 : 16;
    const int n1  = (wave == 0) ? 6 : 5;

    float mem1[6] = {0.f,0.f,0.f,0.f,0.f,0.f};
    float mem2[2] = {0.f,0.f};
    float mem3[6] = {0.f,0.f,0.f,0.f,0.f,0.f};
    float mem4 = 0.f;
    float cnt  = 0.f;
    const float thr4 = thr4p[0];

    const float4* __restrict__ xv4 = (const float4*)x;
    const float4* __restrict__ W1v = (const float4*)W1;

    // ---- t-invariant setup ----
    int  k1v[6]; bool val1[6]; float bsv1[6];
    #pragma unroll
    for (int u = 0; u < 6; ++u) {
        k1v[u] = (c1b + u) * 64 + lane;
        val1[u] = (u < n1) && (k1v[u] < N1);
        bsv1[u] = val1[u] ? bs1[k1v[u]] : 0.f;
    }
    const bool  has2  = (tid < 84);            // owns neuron tid+256 in layer 2
    const float bs2v0 = bs2[tid];
    const float bs2v1 = has2 ? bs2[tid + 256] : 0.f;
    float bs3v[6];
    #pragma unroll
    for (int k = 0; k < 5; ++k) bs3v[k] = bs3[tid + 256 * k];
    bs3v[5] = (tid < 120) ? bs3[tid + 1280] : 0.f;
    const float bs4v = bs4[lane & 3];

    // clamped secondary-chunk offsets + 0/1 masks (avoid divergence in gathers)
    const int   so2    = (lane < 21) ? 4 * lane : 80;    // layer-2 cols 256..339
    const float mask21 = (lane < 21) ? 1.f : 0.f;
    const int   so3    = (lane < 30) ? 4 * lane : 116;   // layer-3 cols 1280..1399
    const float mask30 = (lane < 30) ? 1.f : 0.f;

    for (int t = 0; t < T_STEPS; ++t) {
        float4 xv = xv4[b * T_STEPS + t];
        const float x0 = xv.x / 50.0f + 0.001f;
        const float x1 = xv.y / 50.0f + 0.001f;
        const float x2 = xv.z / 50.0f + 0.001f;
        const float x3 = xv.w / 50.0f + 0.001f;

        // ---------- layer 1 + LIF + own-wave list (entries premult by N2) ----------
        unsigned cnt1w = 0;
        #pragma unroll
        for (int u = 0; u < 6; ++u) {
            if (u < n1) {
                float h = 0.f;
                if (val1[u]) {
                    float4 wv = W1v[k1v[u]];
                    h = bsv1[u] + wv.x * x0 + wv.y * x1 + wv.z * x2 + wv.w * x3;
                }
                float m = mem1[u];
                const float r = (m > 1.0f) ? 1.0f : 0.0f;
                m = 0.9f * m + h - r;
                mem1[u] = m;
                const bool sp = val1[u] && (m > 1.0f);
                const unsigned long long bal = __ballot(sp);
                if (sp) {
                    const int pos = (int)cnt1w + (int)__popcll(bal & ((1ull << lane) - 1ull));
                    lst1[wave * R1 + pos] = (unsigned)(k1v[u] * N2);
                }
                cnt1w += (unsigned)__popcll(bal);
            }
        }

        // ---------- layer-2 gather: own spikes, full 340-col rows ----------
        float4 accA = {0.f,0.f,0.f,0.f};
        float4 accB = {0.f,0.f,0.f,0.f};
        {
            const unsigned* L1w  = lst1 + wave * R1;
            const float* baseA = W2T + 4 * lane;
            const float* baseB = W2T + 256 + so2;
            int j = 0;
            for (; j + 4 <= (int)cnt1w; j += 4) {
                uint4 ov = *(const uint4*)(L1w + j);
                float4 r0 = *(const float4*)(baseA + ov.x);
                float4 r1 = *(const float4*)(baseA + ov.y);
                float4 r2 = *(const float4*)(baseA + ov.z);
                float4 r3 = *(const float4*)(baseA + ov.w);
                float4 s0 = *(const float4*)(baseB + ov.x);
                float4 s1 = *(const float4*)(baseB + ov.y);
                float4 s2 = *(const float4*)(baseB + ov.z);
                float4 s3 = *(const float4*)(baseB + ov.w);
                accA.x += r0.x; accA.y += r0.y; accA.z += r0.z; accA.w += r0.w;
                accB.x += s0.x * mask21; accB.y += s0.y * mask21; accB.z += s0.z * mask21; accB.w += s0.w * mask21;
                accA.x += r1.x; accA.y += r1.y; accA.z += r1.z; accA.w += r1.w;
                accB.x += s1.x * mask21; accB.y += s1.y * mask21; accB.z += s1.z * mask21; accB.w += s1.w * mask21;
                accA.x += r2.x; accA.y += r2.y; accA.z += r2.z; accA.w += r2.w;
                accB.x += s2.x * mask21; accB.y += s2.y * mask21; accB.z += s2.z * mask21; accB.w += s2.w * mask21;
                accA.x += r3.x; accA.y += r3.y; accA.z += r3.z; accA.w += r3.w;
                accB.x += s3.x * mask21; accB.y += s3.y * mask21; accB.z += s3.z * mask21; accB.w += s3.w * mask21;
            }
            for (; j < (int)cnt1w; ++j) {
                const unsigned o = L1w[j];
                float4 r = *(const float4*)(baseA + o);
                float4 s = *(const float4*)(baseB + o);
                accA.x += r.x; accA.y += r.y; accA.z += r.z; accA.w += r.w;
                accB.x += s.x * mask21; accB.y += s.y * mask21; accB.z += s.z * mask21; accB.w += s.w * mask21;
            }
        }
        *(float4*)&pw2[wave][4 * lane] = accA;
        if (lane < 21) *(float4*)&pw2[wave][256 + 4 * lane] = accB;
        __syncthreads();  // B1: pw2 ready

        // ---------- LIF-2 (thread-linear: neurons tid, tid+256) + own list ----------
        unsigned cnt2w = 0;
        {
            const float h0 = pw2[0][tid] + pw2[1][tid] + pw2[2][tid] + pw2[3][tid] + bs2v0;
            float m = mem2[0];
            const float r = (m > 1.0f) ? 1.0f : 0.0f;
            m = 0.9f * m + h0 - r;
            mem2[0] = m;
            const bool sp0 = (m > 1.0f);
            const unsigned long long bal0 = __ballot(sp0);
            if (sp0) {
                const int pos = (int)__popcll(bal0 & ((1ull << lane) - 1ull));
                lst2[wave * R2 + pos] = (unsigned)(tid * N3);
            }
            cnt2w += (unsigned)__popcll(bal0);

            float h1 = 0.f;
            if (has2) h1 = pw2[0][tid+256] + pw2[1][tid+256] + pw2[2][tid+256] + pw2[3][tid+256] + bs2v1;
            float m1v = mem2[1];
            const float r1v = (m1v > 1.0f) ? 1.0f : 0.0f;
            m1v = 0.9f * m1v + h1 - r1v;
            mem2[1] = m1v;
            const bool sp1 = has2 && (m1v > 1.0f);
            const unsigned long long bal1 = __ballot(sp1);
            if (sp1) {
                const int pos = (int)cnt2w + (int)__popcll(bal1 & ((1ull << lane) - 1ull));
                lst2[wave * R2 + pos] = (unsigned)((tid + 256) * N3);
            }
            cnt2w += (unsigned)__popcll(bal1);
        }

        // ---------- layer-3 gather: own spikes, full 1400-col rows ----------
        float4 acc3[6];
        #pragma unroll
        for (int c = 0; c < 6; ++c) acc3[c] = (float4){0.f,0.f,0.f,0.f};
        {
            const unsigned* L2w = lst2 + wave * R2;
            int j = 0;
            for (; j + 2 <= (int)cnt2w; j += 2) {
                uint2 ov = *(const uint2*)(L2w + j);
                const float* ra = W3T + ov.x;
                const float* rb = W3T + ov.y;
                float4 a0 = *(const float4*)(ra + 4*lane);
                float4 a1 = *(const float4*)(ra + 256 + 4*lane);
                float4 a2 = *(const float4*)(ra + 512 + 4*lane);
                float4 a3 = *(const float4*)(ra + 768 + 4*lane);
                float4 a4 = *(const float4*)(ra + 1024 + 4*lane);
                float4 a5 = *(const float4*)(ra + 1280 + so3);
                float4 b0 = *(const float4*)(rb + 4*lane);
                float4 b1_ = *(const float4*)(rb + 256 + 4*lane);
                float4 b2_ = *(const float4*)(rb + 512 + 4*lane);
                float4 b3_ = *(const float4*)(rb + 768 + 4*lane);
                float4 b4_ = *(const float4*)(rb + 1024 + 4*lane);
                float4 b5_ = *(const float4*)(rb + 1280 + so3);
                acc3[0].x += a0.x; acc3[0].y += a0.y; acc3[0].z += a0.z; acc3[0].w += a0.w;
                acc3[1].x += a1.x; acc3[1].y += a1.y; acc3[1].z += a1.z; acc3[1].w += a1.w;
                acc3[2].x += a2.x; acc3[2].y += a2.y; acc3[2].z += a2.z; acc3[2].w += a2.w;
                acc3[3].x += a3.x; acc3[3].y += a3.y; acc3[3].z += a3.z; acc3[3].w += a3.w;
                acc3[4].x += a4.x; acc3[4].y += a4.y; acc3[4].z += a4.z; acc3[4].w += a4.w;
                acc3[5].x += a5.x * mask30; acc3[5].y += a5.y * mask30; acc3[5].z += a5.z * mask30; acc3[5].w += a5.w * mask30;
                acc3[0].x += b0.x; acc3[0].y += b0.y; acc3[0].z += b0.z; acc3[0].w += b0.w;
                acc3[1].x += b1_.x; acc3[1].y += b1_.y; acc3[1].z += b1_.z; acc3[1].w += b1_.w;
                acc3[2].x += b2_.x; acc3[2].y += b2_.y; acc3[2].z += b2_.z; acc3[2].w += b2_.w;
                acc3[3].x += b3_.x; acc3[3].y += b3_.y; acc3[3].z += b3_.z; acc3[3].w += b3_.w;
                acc3[4].x += b4_.x; acc3[4].y += b4_.y; acc3[4].z += b4_.z; acc3[4].w += b4_.w;
                acc3[5].x += b5_.x * mask30; acc3[5].y += b5_.y * mask30; acc3[5].z += b5_.z * mask30; acc3[5].w += b5_.w * mask30;
            }
            for (; j < (int)cnt2w; ++j) {
                const float* ra = W3T + L2w[j];
                float4 a0 = *(const float4*)(ra + 4*lane);
                float4 a1 = *(const float4*)(ra + 256 + 4*lane);
                float4 a2 = *(const float4*)(ra + 512 + 4*lane);
                float4 a3 = *(const float4*)(ra + 768 + 4*lane);
                float4 a4 = *(const float4*)(ra + 1024 + 4*lane);
                float4 a5 = *(const float4*)(ra + 1280 + so3);
                acc3[0].x += a0.x; acc3[0].y += a0.y; acc3[0].z += a0.z; acc3[0].w += a0.w;
                acc3[1].x += a1.x; acc3[1].y += a1.y; acc3[1].z += a1.z; acc3[1].w += a1.w;
                acc3[2].x += a2.x; acc3[2].y += a2.y; acc3[2].z += a2.z; acc3[2].w += a2.w;
                acc3[3].x += a3.x; acc3[3].y += a3.y; acc3[3].z += a3.z; acc3[3].w += a3.w;
                acc3[4].x += a4.x; acc3[4].y += a4.y; acc3[4].z += a4.z; acc3[4].w += a4.w;
                acc3[5].x += a5.x * mask30; acc3[5].y += a5.y * mask30; acc3[5].z += a5.z * mask30; acc3[5].w += a5.w * mask30;
            }
        }
        #pragma unroll
        for (int c = 0; c < 5; ++c)
            *(float4*)&pw3[wave][c * 256 + 4 * lane] = acc3[c];
        if (lane < 30) *(float4*)&pw3[wave][1280 + 4 * lane] = acc3[5];
        __syncthreads();  // B2: pw3 ready

        // ---------- LIF-3 (thread-linear: neurons tid+256k) + own list ----------
        unsigned cnt3w = 0;
        #pragma unroll
        for (int k = 0; k < 6; ++k) {
            const bool valid = (k < 5) || (tid < 120);
            const int n = tid + 256 * k;
            float h = 0.f;
            if (valid) h = pw3[0][n] + pw3[1][n] + pw3[2][n] + pw3[3][n] + bs3v[k];
            float m = mem3[k];
            const float r = (m > 1.0f) ? 1.0f : 0.0f;
            m = 0.9f * m + h - r;
            mem3[k] = m;
            const bool sp = valid && (m > 1.0f);
            const unsigned long long bal = __ballot(sp);
            if (sp) {
                const int pos = (int)cnt3w + (int)__popcll(bal & ((1ull << lane) - 1ull));
                lst3[wave * R3 + pos] = (unsigned)(n * 4);
            }
            cnt3w += (unsigned)__popcll(bal);
        }
        if (lane == 0) wcnt3[wave] = (int)cnt3w;
        __syncthreads();  // B3: lst3/wcnt3 ready

        // ---------- layer 4 on wave 3, 64-lane parallel ----------
        // (other waves proceed into t+1; lst3/wcnt3 are not rewritten until
        //  after B2(t+1), which requires wave 3 to have finished here)
        if (wave == 3) {
            const int g16 = lane >> 2;
            const int o4  = lane & 3;
            float h4p = 0.f;
            for (int w = 0; w < 4; ++w) {
                const int n = wcnt3[w];
                const unsigned* Lw = lst3 + w * R3;
                int j = g16;
                for (; j + 48 < n; j += 64) {
                    float t0 = W4T[Lw[j]      + o4];
                    float t1 = W4T[Lw[j + 16] + o4];
                    float t2 = W4T[Lw[j + 32] + o4];
                    float t3 = W4T[Lw[j + 48] + o4];
                    h4p += t0; h4p += t1; h4p += t2; h4p += t3;
                }
                for (; j < n; j += 16) h4p += W4T[Lw[j] + o4];
            }
            #pragma unroll
            for (int d = 4; d < 64; d <<= 1) h4p += __shfl_xor(h4p, d);
            float h4 = bs4v + h4p;
            float m4 = mem4;
            const float r4 = (m4 > thr4) ? thr4 : 0.f;
            m4 = 0.9f * m4 + h4 - r4;
            mem4 = m4;
            const float s4 = (m4 > thr4) ? 1.f : 0.f;
            if (lane < 4) {
                sbuf[t * 4 + lane] = s4;
                cnt += s4;
            }
        }
    }

    __syncthreads();  // sbuf complete
    for (int i = threadIdx.x; i < T_STEPS * 4; i += 256)
        out[8192 + b * T_STEPS * 4 + i] = sbuf[i];
    if (wave == 3 && lane < 4) out[b * 4 + lane] = cnt;
}

extern "C" void kernel_launch(void* const* d_in, const int* in_sizes, int n_in,
                              void* d_out, int out_size, void* d_ws, size_t ws_size,
                              hipStream_t stream)
{
    const float* x     = (const float*)d_in[0];
    const float* W1    = (const float*)d_in[1];
    const float* b1    = (const float*)d_in[2];
    const float* bias1 = (const float*)d_in[3];
    const float* W2    = (const float*)d_in[4];
    const float* b2    = (const float*)d_in[5];
    const float* bias2 = (const float*)d_in[6];
    const float* W3    = (const float*)d_in[7];
    const float* b3    = (const float*)d_in[8];
    const float* bias3 = (const float*)d_in[9];
    const float* W4    = (const float*)d_in[10];
    const float* b4    = (const float*)d_in[11];
    const float* bias4 = (const float*)d_in[12];
    const float* thr4  = (const float*)d_in[13];
    float* out = (float*)d_out;
    float* ws  = (float*)d_ws;

    hipLaunchKernelGGL(snn_prep, dim3(1024), dim3(256), 0, stream,
                       W2, W3, W4, b1, bias1, b2, bias2, b3, bias3, b4, bias4, ws);
    hipLaunchKernelGGL(snn_main, dim3(B_ROWS), dim3(256), 0, stream,
                       x, W1, ws, thr4, out);
}